// Round 10
// baseline (148.196 us; speedup 1.0000x reference)
//
#include <hip/hip_runtime.h>

// Bidirectional LSTM, B=16384 T=512 I=1 H=8, + final linear on [h_f(T-1), h_b(T-1)].
// Backward direction's state at time T-1 is its FIRST scan step -> one step only.
//
// R10 = R8 structure x ILP-2: each thread runs TWO independent batch elements
// (e0=2p, e1=2p+1) through the scan simultaneously.
//  - Grid: (B/2)*8 threads = 1024 waves = 1 wave/SIMD. Element B's independent
//    FMA stream fills every stall of element A (swizzle lgkmcnt, exp->rcp tail)
//    via in-wave ILP -- the ~100-150 cyc/step idle seen in R8 (wave-switch
//    couldn't fully cover) and R9 (no second stream at all).
//  - Weights (40 VGPRs) are SHARED by both elements: loaded once per thread.
//  - Cell-tanh rcp paired ACROSS elements (R9-validated trick): 15 trans / 2 elems.
//  - Kept from R8: hybrid broadcast (4 own-quad quad_perm DPP + 4 cross-quad
//    bit-mode ds_swizzles per element), activation scales folded into weights
//    (i,f,o rows x -log2e; g row x +2log2e), paired gate reciprocals, cell
//    state pre-scaled by 2log2e, unconditional software-pipelined x prefetch.

#define LOG2E 1.4426950408889634f

// quad_perm broadcast lane k within each 4-lane quad (k = 0..3): ctrl = k * 0x55
#define DPPQ(v, k) __int_as_float(__builtin_amdgcn_update_dpp(0, __float_as_int(v), ((k) * 0x55), 0xF, 0xF, true))
// cross-quad pull: src = ((i & 0x1C) | k) ^ 4  -> quad0 gets h[4+k], quad1 gets h[k]
#define SWZX(v, k) __int_as_float(__builtin_amdgcn_ds_swizzle(__float_as_int(v), ((4 << 10) | ((k) << 5) | 0x1C)))

struct Ctx {
    float wi[8], wf[8], wg[8], wo[8];  // recurrent rows, pre-scaled + slot-permuted
    float xi, xf, xg, xo;              // input weights, pre-scaled
    float bi, bf, bg, bo;              // biases, pre-scaled
};

__device__ __forceinline__ void load_ctx(Ctx& C, int j, int qp,
    const float* __restrict__ w_ih, const float* __restrict__ w_hh,
    const float* __restrict__ b)
{
    // slot k -> h index: k<4 -> qp*4+k ; k>=4 -> (1-qp)*4 + (k-4)
    int own = qp * 4;
    int oth = 4 - own;
    const float si = -LOG2E;           // sigma rows: e = exp2(-z*log2e) = e^-z
    const float sg = 2.0f * LOG2E;     // tanh row:  e = exp2(2z*log2e) = e^{2z}

    const float* ri = w_hh + (size_t)j * 8;
    const float* rf = w_hh + (size_t)(8 + j) * 8;
    const float* rg = w_hh + (size_t)(16 + j) * 8;
    const float* ro = w_hh + (size_t)(24 + j) * 8;
#pragma unroll
    for (int k = 0; k < 8; ++k) {
        int src = (k < 4) ? (own + k) : (oth + k - 4);
        C.wi[k] = ri[src] * si;
        C.wf[k] = rf[src] * si;
        C.wg[k] = rg[src] * sg;
        C.wo[k] = ro[src] * si;
    }
    C.xi = w_ih[j] * si;      C.bi = b[j] * si;
    C.xf = w_ih[8 + j] * si;  C.bf = b[8 + j] * si;
    C.xg = w_ih[16 + j] * sg; C.bg = b[16 + j] * sg;
    C.xo = w_ih[24 + j] * si; C.bo = b[24 + j] * si;
}

// Two independent elements per call; cs* pre-scaled by 2*log2(e).
__device__ __forceinline__ void lstm_step2(float xtA, float xtB,
    float& hA, float& csA, float& hB, float& csB, const Ctx& C)
{
    // cross-quad slots via DS pipe for both elements (latency hidden by the
    // other element's DPP-fed fma work)
    float a4 = SWZX(hA, 0), a5 = SWZX(hA, 1), a6 = SWZX(hA, 2), a7 = SWZX(hA, 3);
    float b4 = SWZX(hB, 0), b5 = SWZX(hB, 1), b6 = SWZX(hB, 2), b7 = SWZX(hB, 3);
    // own-quad slots via quad_perm DPP (ready immediately)
    float a0 = DPPQ(hA, 0), a1 = DPPQ(hA, 1), a2 = DPPQ(hA, 2), a3 = DPPQ(hA, 3);
    float b0 = DPPQ(hB, 0), b1 = DPPQ(hB, 1), b2 = DPPQ(hB, 2), b3 = DPPQ(hB, 3);

    float ziA = fmaf(xtA, C.xi, C.bi), ziB = fmaf(xtB, C.xi, C.bi);
    float zfA = fmaf(xtA, C.xf, C.bf), zfB = fmaf(xtB, C.xf, C.bf);
    float zgA = fmaf(xtA, C.xg, C.bg), zgB = fmaf(xtB, C.xg, C.bg);
    float zoA = fmaf(xtA, C.xo, C.bo), zoB = fmaf(xtB, C.xo, C.bo);

    ziA = fmaf(a0, C.wi[0], ziA); zfA = fmaf(a0, C.wf[0], zfA);
    zgA = fmaf(a0, C.wg[0], zgA); zoA = fmaf(a0, C.wo[0], zoA);
    ziB = fmaf(b0, C.wi[0], ziB); zfB = fmaf(b0, C.wf[0], zfB);
    zgB = fmaf(b0, C.wg[0], zgB); zoB = fmaf(b0, C.wo[0], zoB);
    ziA = fmaf(a1, C.wi[1], ziA); zfA = fmaf(a1, C.wf[1], zfA);
    zgA = fmaf(a1, C.wg[1], zgA); zoA = fmaf(a1, C.wo[1], zoA);
    ziB = fmaf(b1, C.wi[1], ziB); zfB = fmaf(b1, C.wf[1], zfB);
    zgB = fmaf(b1, C.wg[1], zgB); zoB = fmaf(b1, C.wo[1], zoB);
    ziA = fmaf(a2, C.wi[2], ziA); zfA = fmaf(a2, C.wf[2], zfA);
    zgA = fmaf(a2, C.wg[2], zgA); zoA = fmaf(a2, C.wo[2], zoA);
    ziB = fmaf(b2, C.wi[2], ziB); zfB = fmaf(b2, C.wf[2], zfB);
    zgB = fmaf(b2, C.wg[2], zgB); zoB = fmaf(b2, C.wo[2], zoB);
    ziA = fmaf(a3, C.wi[3], ziA); zfA = fmaf(a3, C.wf[3], zfA);
    zgA = fmaf(a3, C.wg[3], zgA); zoA = fmaf(a3, C.wo[3], zoA);
    ziB = fmaf(b3, C.wi[3], ziB); zfB = fmaf(b3, C.wf[3], zfB);
    zgB = fmaf(b3, C.wg[3], zgB); zoB = fmaf(b3, C.wo[3], zoB);
    ziA = fmaf(a4, C.wi[4], ziA); zfA = fmaf(a4, C.wf[4], zfA);
    zgA = fmaf(a4, C.wg[4], zgA); zoA = fmaf(a4, C.wo[4], zoA);
    ziB = fmaf(b4, C.wi[4], ziB); zfB = fmaf(b4, C.wf[4], zfB);
    zgB = fmaf(b4, C.wg[4], zgB); zoB = fmaf(b4, C.wo[4], zoB);
    ziA = fmaf(a5, C.wi[5], ziA); zfA = fmaf(a5, C.wf[5], zfA);
    zgA = fmaf(a5, C.wg[5], zgA); zoA = fmaf(a5, C.wo[5], zoA);
    ziB = fmaf(b5, C.wi[5], ziB); zfB = fmaf(b5, C.wf[5], zfB);
    zgB = fmaf(b5, C.wg[5], zgB); zoB = fmaf(b5, C.wo[5], zoB);
    ziA = fmaf(a6, C.wi[6], ziA); zfA = fmaf(a6, C.wf[6], zfA);
    zgA = fmaf(a6, C.wg[6], zgA); zoA = fmaf(a6, C.wo[6], zoA);
    ziB = fmaf(b6, C.wi[6], ziB); zfB = fmaf(b6, C.wf[6], zfB);
    zgB = fmaf(b6, C.wg[6], zgB); zoB = fmaf(b6, C.wo[6], zoB);
    ziA = fmaf(a7, C.wi[7], ziA); zfA = fmaf(a7, C.wf[7], zfA);
    zgA = fmaf(a7, C.wg[7], zgA); zoA = fmaf(a7, C.wo[7], zoA);
    ziB = fmaf(b7, C.wi[7], ziB); zfB = fmaf(b7, C.wf[7], zfB);
    zgB = fmaf(b7, C.wg[7], zgB); zoB = fmaf(b7, C.wo[7], zoB);

    float eiA = __builtin_amdgcn_exp2f(ziA);   // e^{-i}
    float efA = __builtin_amdgcn_exp2f(zfA);   // e^{-f}
    float egA = __builtin_amdgcn_exp2f(zgA);   // e^{2g}
    float eoA = __builtin_amdgcn_exp2f(zoA);   // e^{-o}
    float eiB = __builtin_amdgcn_exp2f(ziB);
    float efB = __builtin_amdgcn_exp2f(zfB);
    float egB = __builtin_amdgcn_exp2f(zgB);
    float eoB = __builtin_amdgcn_exp2f(zoB);

    float diA = 1.0f + eiA, dfA = 1.0f + efA;
    float dgA = 1.0f + egA, doA = 1.0f + eoA;
    float diB = 1.0f + eiB, dfB = 1.0f + efB;
    float dgB = 1.0f + egB, doB = 1.0f + eoB;

    // paired reciprocals per element: 2 rcp serve 4 gates
    float RaA = __builtin_amdgcn_rcpf(diA * dfA);
    float sigiA = RaA * dfA, sigfA = RaA * diA;
    float RbA = __builtin_amdgcn_rcpf(dgA * doA);
    float qgA = RbA * doA, sigoA = RbA * dgA;
    float RaB = __builtin_amdgcn_rcpf(diB * dfB);
    float sigiB = RaB * dfB, sigfB = RaB * diB;
    float RbB = __builtin_amdgcn_rcpf(dgB * doB);
    float qgB = RbB * doB, sigoB = RbB * dgB;

    // tgs = 2*log2(e)*tanh(g)
    float tgsA = fmaf(-4.0f * LOG2E, qgA, 2.0f * LOG2E);
    float tgsB = fmaf(-4.0f * LOG2E, qgB, 2.0f * LOG2E);
    csA = fmaf(sigfA, csA, sigiA * tgsA);
    csB = fmaf(sigfB, csB, sigiB * tgsB);

    // tanh(c) = 1 - 2/(1+e^{2c}); e^{2c} = exp2(cs). Cell rcp paired ACROSS elements.
    float ecA = __builtin_amdgcn_exp2f(csA);
    float ecB = __builtin_amdgcn_exp2f(csB);
    float dcA = 1.0f + ecA, dcB = 1.0f + ecB;
    float Rc = __builtin_amdgcn_rcpf(dcA * dcB);
    float qcA = Rc * dcB, qcB = Rc * dcA;
    hA = sigoA * fmaf(-2.0f, qcA, 1.0f);
    hB = sigoB * fmaf(-2.0f, qcB, 1.0f);
}

__global__ __launch_bounds__(256, 1) void bilstm_kernel(
    const float* __restrict__ x, const float* __restrict__ h0, const float* __restrict__ c0,
    const float* __restrict__ w_ih_f, const float* __restrict__ w_hh_f, const float* __restrict__ b_f,
    const float* __restrict__ w_ih_b, const float* __restrict__ w_hh_b, const float* __restrict__ b_b,
    const float* __restrict__ w_lin, const float* __restrict__ b_lin,
    float* __restrict__ out, int B, int T)
{
    int tid = blockIdx.x * 256 + threadIdx.x;
    int p = tid >> 3;                  // element-pair index
    int j = tid & 7;
    int qp = (threadIdx.x >> 2) & 1;   // quad parity within the 8-lane group
    if (p >= (B >> 1)) return;
    int e0 = 2 * p, e1 = 2 * p + 1;

    Ctx Cf;
    load_ctx(Cf, j, qp, w_ih_f, w_hh_f, b_f);

    float hA  = h0[(size_t)e0 * 8 + j];
    float hB  = h0[(size_t)e1 * 8 + j];
    float csA = c0[(size_t)e0 * 8 + j] * (2.0f * LOG2E);
    float csB = c0[(size_t)e1 * 8 + j] * (2.0f * LOG2E);

    const float4* xrA = (const float4*)(x + (size_t)e0 * T);
    const float4* xrB = (const float4*)(x + (size_t)e1 * T);
    int nT4 = T >> 2;
    float4 xvA = xrA[0];
    float4 xvB = xrB[0];
    // software pipeline: load group t4+1 unconditionally, use group t4
    for (int t4 = 0; t4 < nT4 - 1; ++t4) {
        float4 nA = xrA[t4 + 1];
        float4 nB = xrB[t4 + 1];
        lstm_step2(xvA.x, xvB.x, hA, csA, hB, csB, Cf);
        lstm_step2(xvA.y, xvB.y, hA, csA, hB, csB, Cf);
        lstm_step2(xvA.z, xvB.z, hA, csA, hB, csB, Cf);
        lstm_step2(xvA.w, xvB.w, hA, csA, hB, csB, Cf);
        xvA = nA; xvB = nB;
    }
    // epilogue: last group
    lstm_step2(xvA.x, xvB.x, hA, csA, hB, csB, Cf);
    lstm_step2(xvA.y, xvB.y, hA, csA, hB, csB, Cf);
    lstm_step2(xvA.z, xvB.z, hA, csA, hB, csB, Cf);
    float xlastA = xvA.w, xlastB = xvB.w;
    lstm_step2(xlastA, xlastB, hA, csA, hB, csB, Cf);

    // backward direction: exactly one step on x[:, T-1]
    Ctx Cb;
    load_ctx(Cb, j, qp, w_ih_b, w_hh_b, b_b);
    float hbA  = h0[(size_t)B * 8 + (size_t)e0 * 8 + j];
    float hbB  = h0[(size_t)B * 8 + (size_t)e1 * 8 + j];
    float cbA  = c0[(size_t)B * 8 + (size_t)e0 * 8 + j] * (2.0f * LOG2E);
    float cbB  = c0[(size_t)B * 8 + (size_t)e1 * 8 + j] * (2.0f * LOG2E);
    lstm_step2(xlastA, xlastB, hbA, cbA, hbB, cbB, Cb);

    // final linear per element, reduced across the 8-lane group
    float pA = fmaf(hA, w_lin[j], hbA * w_lin[8 + j]);
    float pB = fmaf(hB, w_lin[j], hbB * w_lin[8 + j]);
    pA += __shfl_xor(pA, 1, 8);
    pB += __shfl_xor(pB, 1, 8);
    pA += __shfl_xor(pA, 2, 8);
    pB += __shfl_xor(pB, 2, 8);
    pA += __shfl_xor(pA, 4, 8);
    pB += __shfl_xor(pB, 4, 8);
    if (j == 0) {
        float bl = b_lin[0];
        out[e0] = pA + bl;
        out[e1] = pB + bl;
    }
}

extern "C" void kernel_launch(void* const* d_in, const int* in_sizes, int n_in,
                              void* d_out, int out_size, void* d_ws, size_t ws_size,
                              hipStream_t stream)
{
    const float* x      = (const float*)d_in[0];
    const float* h0     = (const float*)d_in[1];
    const float* c0     = (const float*)d_in[2];
    const float* w_ih_f = (const float*)d_in[3];
    const float* w_hh_f = (const float*)d_in[4];
    const float* b_f    = (const float*)d_in[5];
    const float* w_ih_b = (const float*)d_in[6];
    const float* w_hh_b = (const float*)d_in[7];
    const float* b_b    = (const float*)d_in[8];
    const float* w_lin  = (const float*)d_in[9];
    const float* b_lin  = (const float*)d_in[10];
    float* out = (float*)d_out;

    int B = in_sizes[1] / 16;   // h0: (2, B, 8)
    int T = in_sizes[0] / B;    // x:  (B, T, 1)

    int threads = (B / 2) * 8;
    dim3 block(256);
    dim3 grid((threads + 255) / 256);
    hipLaunchKernelGGL(bilstm_kernel, grid, block, 0, stream,
                       x, h0, c0, w_ih_f, w_hh_f, b_f, w_ih_b, w_hh_b, b_b,
                       w_lin, b_lin, out, B, T);
}

// Round 11
// 128.378 us; speedup vs baseline: 1.1544x; 1.1544x over previous
//
#include <hip/hip_runtime.h>

// Bidirectional LSTM, B=16384 T=512 I=1 H=8, + final linear on [h_f(T-1), h_b(T-1)].
// Backward direction's state at time T-1 is its FIRST scan step -> one step only.
//
// R11 = R8 + VGPR-pinned weights.
//  Diagnosis: R1..R10 all report VGPR_Count=40-64 while the steady-state loop
//  needs ~65+ live values (40 Ctx + h/cs/xv/hk/z/addr). The compiler was
//  SINKING the weight loads into the K-loop (re-loading ~40 L1-cached scalars
//  per step) -- invisible in FETCH_SIZE (cache hits) and WRITE_SIZE (no spill)
//  but costing ~230 busy-cyc/SIMD-step of global_load issue + vmcnt waits (the
//  gap between the instruction-count model ~356 cyc and measured 588).
//  Fix: empty asm "+v" barriers after load_ctx make the 40 weights opaque asm
//  results -> cannot be rematerialized or re-loaded, must stay in VGPRs.
//  Everything else identical to R8 (hybrid DPP+swizzle broadcast, folded
//  activation scales, paired rcp, pre-scaled cell, unconditional x prefetch).

#define LOG2E 1.4426950408889634f

// quad_perm broadcast lane k within each 4-lane quad (k = 0..3): ctrl = k * 0x55
#define DPPQ(v, k) __int_as_float(__builtin_amdgcn_update_dpp(0, __float_as_int(v), ((k) * 0x55), 0xF, 0xF, true))
// cross-quad pull: src = ((i & 0x1C) | k) ^ 4  -> quad0 gets h[4+k], quad1 gets h[k]
#define SWZX(v, k) __int_as_float(__builtin_amdgcn_ds_swizzle(__float_as_int(v), ((4 << 10) | ((k) << 5) | 0x1C)))

struct Ctx {
    float wi[8], wf[8], wg[8], wo[8];  // recurrent rows, pre-scaled + slot-permuted
    float xi, xf, xg, xo;              // input weights, pre-scaled
    float bi, bf, bg, bo;              // biases, pre-scaled
};

__device__ __forceinline__ void load_ctx(Ctx& C, int j, int qp,
    const float* __restrict__ w_ih, const float* __restrict__ w_hh,
    const float* __restrict__ b)
{
    // slot k -> h index: k<4 -> qp*4+k ; k>=4 -> (1-qp)*4 + (k-4)
    int own = qp * 4;
    int oth = 4 - own;
    const float si = -LOG2E;           // sigma rows: e = exp2(-z*log2e) = e^-z
    const float sg = 2.0f * LOG2E;     // tanh row:  e = exp2(2z*log2e) = e^{2z}

    const float* ri = w_hh + (size_t)j * 8;
    const float* rf = w_hh + (size_t)(8 + j) * 8;
    const float* rg = w_hh + (size_t)(16 + j) * 8;
    const float* ro = w_hh + (size_t)(24 + j) * 8;
#pragma unroll
    for (int k = 0; k < 8; ++k) {
        int src = (k < 4) ? (own + k) : (oth + k - 4);
        C.wi[k] = ri[src] * si;
        C.wf[k] = rf[src] * si;
        C.wg[k] = rg[src] * sg;
        C.wo[k] = ro[src] * si;
    }
    C.xi = w_ih[j] * si;      C.bi = b[j] * si;
    C.xf = w_ih[8 + j] * si;  C.bf = b[8 + j] * si;
    C.xg = w_ih[16 + j] * sg; C.bg = b[16 + j] * sg;
    C.xo = w_ih[24 + j] * si; C.bo = b[24 + j] * si;
}

// Force every Ctx value to be a live VGPR (opaque to rematerialization/reload).
__device__ __forceinline__ void pin_ctx(Ctx& C)
{
#pragma unroll
    for (int k = 0; k < 8; ++k) {
        asm volatile("" : "+v"(C.wi[k]), "+v"(C.wf[k]), "+v"(C.wg[k]), "+v"(C.wo[k]));
    }
    asm volatile("" : "+v"(C.xi), "+v"(C.xf), "+v"(C.xg), "+v"(C.xo));
    asm volatile("" : "+v"(C.bi), "+v"(C.bf), "+v"(C.bg), "+v"(C.bo));
}

// cs is the cell state pre-scaled by 2*log2(e).
__device__ __forceinline__ void lstm_step(float xt, float& h, float& cs, const Ctx& C)
{
    // slots 4-7: cross-quad values via DS pipe (latency hidden under the DPP
    // slots' fma work)
    float hk4 = SWZX(h, 0);
    float hk5 = SWZX(h, 1);
    float hk6 = SWZX(h, 2);
    float hk7 = SWZX(h, 3);
    // slots 0-3: own-quad values via quad_perm DPP (ready immediately)
    float hk0 = DPPQ(h, 0);
    float hk1 = DPPQ(h, 1);
    float hk2 = DPPQ(h, 2);
    float hk3 = DPPQ(h, 3);

    float zi = fmaf(xt, C.xi, C.bi);
    float zf = fmaf(xt, C.xf, C.bf);
    float zg = fmaf(xt, C.xg, C.bg);
    float zo = fmaf(xt, C.xo, C.bo);

    zi = fmaf(hk0, C.wi[0], zi); zf = fmaf(hk0, C.wf[0], zf);
    zg = fmaf(hk0, C.wg[0], zg); zo = fmaf(hk0, C.wo[0], zo);
    zi = fmaf(hk1, C.wi[1], zi); zf = fmaf(hk1, C.wf[1], zf);
    zg = fmaf(hk1, C.wg[1], zg); zo = fmaf(hk1, C.wo[1], zo);
    zi = fmaf(hk2, C.wi[2], zi); zf = fmaf(hk2, C.wf[2], zf);
    zg = fmaf(hk2, C.wg[2], zg); zo = fmaf(hk2, C.wo[2], zo);
    zi = fmaf(hk3, C.wi[3], zi); zf = fmaf(hk3, C.wf[3], zf);
    zg = fmaf(hk3, C.wg[3], zg); zo = fmaf(hk3, C.wo[3], zo);
    zi = fmaf(hk4, C.wi[4], zi); zf = fmaf(hk4, C.wf[4], zf);
    zg = fmaf(hk4, C.wg[4], zg); zo = fmaf(hk4, C.wo[4], zo);
    zi = fmaf(hk5, C.wi[5], zi); zf = fmaf(hk5, C.wf[5], zf);
    zg = fmaf(hk5, C.wg[5], zg); zo = fmaf(hk5, C.wo[5], zo);
    zi = fmaf(hk6, C.wi[6], zi); zf = fmaf(hk6, C.wf[6], zf);
    zg = fmaf(hk6, C.wg[6], zg); zo = fmaf(hk6, C.wo[6], zo);
    zi = fmaf(hk7, C.wi[7], zi); zf = fmaf(hk7, C.wf[7], zf);
    zg = fmaf(hk7, C.wg[7], zg); zo = fmaf(hk7, C.wo[7], zo);

    float ei = __builtin_amdgcn_exp2f(zi);   // e^{-i}
    float ef = __builtin_amdgcn_exp2f(zf);   // e^{-f}
    float eg = __builtin_amdgcn_exp2f(zg);   // e^{2g}
    float eo = __builtin_amdgcn_exp2f(zo);   // e^{-o}
    float di = 1.0f + ei, df = 1.0f + ef;
    float dg = 1.0f + eg, dz = 1.0f + eo;

    // paired reciprocals: 2 rcp for 4 gates
    float Ra = __builtin_amdgcn_rcpf(di * df);
    float sigi = Ra * df;                    // sigma(i)
    float sigf = Ra * di;                    // sigma(f)
    float Rb = __builtin_amdgcn_rcpf(dg * dz);
    float qg   = Rb * dz;                    // 1/(1+e^{2g})
    float sigo = Rb * dg;                    // sigma(o)

    // tgs = 2*log2(e) * tanh(g)
    float tgs = fmaf(-4.0f * LOG2E, qg, 2.0f * LOG2E);
    cs = fmaf(sigf, cs, sigi * tgs);         // scaled cell update
    // tanh(c) = 1 - 2/(1+e^{2c}), and e^{2c} = exp2(cs)
    float ec = __builtin_amdgcn_exp2f(cs);
    float qc = __builtin_amdgcn_rcpf(1.0f + ec);
    h = sigo * fmaf(-2.0f, qc, 1.0f);
}

__global__ __launch_bounds__(256, 2) void bilstm_kernel(
    const float* __restrict__ x, const float* __restrict__ h0, const float* __restrict__ c0,
    const float* __restrict__ w_ih_f, const float* __restrict__ w_hh_f, const float* __restrict__ b_f,
    const float* __restrict__ w_ih_b, const float* __restrict__ w_hh_b, const float* __restrict__ b_b,
    const float* __restrict__ w_lin, const float* __restrict__ b_lin,
    float* __restrict__ out, int B, int T)
{
    int tid = blockIdx.x * 256 + threadIdx.x;
    int b = tid >> 3;
    int j = tid & 7;
    int qp = (threadIdx.x >> 2) & 1;   // quad parity within the 8-lane group
    if (b >= B) return;

    Ctx Cf;
    load_ctx(Cf, j, qp, w_ih_f, w_hh_f, b_f);
    pin_ctx(Cf);                       // force residency: no re-load inside loop

    float h  = h0[(size_t)b * 8 + j];
    float cs = c0[(size_t)b * 8 + j] * (2.0f * LOG2E);

    const float4* xr = (const float4*)(x + (size_t)b * T);
    int nT4 = T >> 2;
    float4 xv = xr[0];
    // software pipeline: load group t4+1 unconditionally, use group t4
    for (int t4 = 0; t4 < nT4 - 1; ++t4) {
        float4 nxt = xr[t4 + 1];
        lstm_step(xv.x, h, cs, Cf);
        lstm_step(xv.y, h, cs, Cf);
        lstm_step(xv.z, h, cs, Cf);
        lstm_step(xv.w, h, cs, Cf);
        xv = nxt;
    }
    // epilogue: last group
    lstm_step(xv.x, h, cs, Cf);
    lstm_step(xv.y, h, cs, Cf);
    lstm_step(xv.z, h, cs, Cf);
    float xlast = xv.w;
    lstm_step(xlast, h, cs, Cf);

    // backward direction: exactly one step on x[:, T-1] (== xv.w)
    Ctx Cb;
    load_ctx(Cb, j, qp, w_ih_b, w_hh_b, b_b);
    float hb  = h0[(size_t)B * 8 + (size_t)b * 8 + j];
    float cbs = c0[(size_t)B * 8 + (size_t)b * 8 + j] * (2.0f * LOG2E);
    lstm_step(xlast, hb, cbs, Cb);

    // final linear: out[b] = sum_j h[j]*wl[j] + hb[j]*wl[8+j] + b_lin
    float part = fmaf(h, w_lin[j], hb * w_lin[8 + j]);
    part += __shfl_xor(part, 1, 8);
    part += __shfl_xor(part, 2, 8);
    part += __shfl_xor(part, 4, 8);
    if (j == 0) out[b] = part + b_lin[0];
}

extern "C" void kernel_launch(void* const* d_in, const int* in_sizes, int n_in,
                              void* d_out, int out_size, void* d_ws, size_t ws_size,
                              hipStream_t stream)
{
    const float* x      = (const float*)d_in[0];
    const float* h0     = (const float*)d_in[1];
    const float* c0     = (const float*)d_in[2];
    const float* w_ih_f = (const float*)d_in[3];
    const float* w_hh_f = (const float*)d_in[4];
    const float* b_f    = (const float*)d_in[5];
    const float* w_ih_b = (const float*)d_in[6];
    const float* w_hh_b = (const float*)d_in[7];
    const float* b_b    = (const float*)d_in[8];
    const float* w_lin  = (const float*)d_in[9];
    const float* b_lin  = (const float*)d_in[10];
    float* out = (float*)d_out;

    int B = in_sizes[1] / 16;   // h0: (2, B, 8)
    int T = in_sizes[0] / B;    // x:  (B, T, 1)

    int threads = B * 8;
    dim3 block(256);
    dim3 grid((threads + 255) / 256);
    hipLaunchKernelGGL(bilstm_kernel, grid, block, 0, stream,
                       x, h0, c0, w_ih_f, w_hh_f, b_f, w_ih_b, w_hh_b, b_b,
                       w_lin, b_lin, out, B, T);
}

// Round 12
// 126.286 us; speedup vs baseline: 1.1735x; 1.0166x over previous
//
#include <hip/hip_runtime.h>

// Bidirectional LSTM, B=16384 T=512 I=1 H=8, + final linear on [h_f(T-1), h_b(T-1)].
// Backward direction's state at time T-1 is its FIRST scan step -> one step only.
//
// R12 = R8 + split-accumulator gate dots (shorter critical chain).
//  Ledger (R8/R11 fit): issue/SIMD-step ~590 cyc busy (trans ~20-24 cyc/instr
//  = 55-65%), stall ~90 cyc = phase-aligned per-step chains of the 2 waves.
//  Change: each gate's 9-deep FMA chain is split into two 5-deep halves
//  (own-quad hk0-3 + x-init | cross-quad hk4-7), merged with one add, g/i/f
//  merged before o (they gate the serial c-update). Chain -16 cyc, issue +8.
//  Kept: hybrid broadcast (4 quad_perm DPP + 4 cross-quad ds_swizzle),
//  activation scales folded into weights, paired reciprocals, cell pre-scaled
//  by 2log2e, unconditional 1-deep x prefetch.

#define LOG2E 1.4426950408889634f

// quad_perm broadcast lane k within each 4-lane quad (k = 0..3): ctrl = k * 0x55
#define DPPQ(v, k) __int_as_float(__builtin_amdgcn_update_dpp(0, __float_as_int(v), ((k) * 0x55), 0xF, 0xF, true))
// cross-quad pull: src = ((i & 0x1C) | k) ^ 4  -> quad0 gets h[4+k], quad1 gets h[k]
#define SWZX(v, k) __int_as_float(__builtin_amdgcn_ds_swizzle(__float_as_int(v), ((4 << 10) | ((k) << 5) | 0x1C)))

struct Ctx {
    float wi[8], wf[8], wg[8], wo[8];  // recurrent rows, pre-scaled + slot-permuted
    float xi, xf, xg, xo;              // input weights, pre-scaled
    float bi, bf, bg, bo;              // biases, pre-scaled
};

__device__ __forceinline__ void load_ctx(Ctx& C, int j, int qp,
    const float* __restrict__ w_ih, const float* __restrict__ w_hh,
    const float* __restrict__ b)
{
    // slot k -> h index: k<4 -> qp*4+k ; k>=4 -> (1-qp)*4 + (k-4)
    int own = qp * 4;
    int oth = 4 - own;
    const float si = -LOG2E;           // sigma rows: e = exp2(-z*log2e) = e^-z
    const float sg = 2.0f * LOG2E;     // tanh row:  e = exp2(2z*log2e) = e^{2z}

    const float* ri = w_hh + (size_t)j * 8;
    const float* rf = w_hh + (size_t)(8 + j) * 8;
    const float* rg = w_hh + (size_t)(16 + j) * 8;
    const float* ro = w_hh + (size_t)(24 + j) * 8;
#pragma unroll
    for (int k = 0; k < 8; ++k) {
        int src = (k < 4) ? (own + k) : (oth + k - 4);
        C.wi[k] = ri[src] * si;
        C.wf[k] = rf[src] * si;
        C.wg[k] = rg[src] * sg;
        C.wo[k] = ro[src] * si;
    }
    C.xi = w_ih[j] * si;      C.bi = b[j] * si;
    C.xf = w_ih[8 + j] * si;  C.bf = b[8 + j] * si;
    C.xg = w_ih[16 + j] * sg; C.bg = b[16 + j] * sg;
    C.xo = w_ih[24 + j] * si; C.bo = b[24 + j] * si;
}

// cs is the cell state pre-scaled by 2*log2(e).
__device__ __forceinline__ void lstm_step(float xt, float& h, float& cs, const Ctx& C)
{
    // slots 4-7: cross-quad values via DS pipe (issued first; latency hidden
    // under the own-quad half's fma work + the other wave)
    float hk4 = SWZX(h, 0);
    float hk5 = SWZX(h, 1);
    float hk6 = SWZX(h, 2);
    float hk7 = SWZX(h, 3);
    // slots 0-3: own-quad values via quad_perm DPP (ready immediately)
    float hk0 = DPPQ(h, 0);
    float hk1 = DPPQ(h, 1);
    float hk2 = DPPQ(h, 2);
    float hk3 = DPPQ(h, 3);

    // half A: x-init + own-quad slots (no DS dependence -> starts immediately)
    float aiA = fmaf(xt, C.xi, C.bi);
    float afA = fmaf(xt, C.xf, C.bf);
    float agA = fmaf(xt, C.xg, C.bg);
    float aoA = fmaf(xt, C.xo, C.bo);
    aiA = fmaf(hk0, C.wi[0], aiA); afA = fmaf(hk0, C.wf[0], afA);
    agA = fmaf(hk0, C.wg[0], agA); aoA = fmaf(hk0, C.wo[0], aoA);
    aiA = fmaf(hk1, C.wi[1], aiA); afA = fmaf(hk1, C.wf[1], afA);
    agA = fmaf(hk1, C.wg[1], agA); aoA = fmaf(hk1, C.wo[1], aoA);
    aiA = fmaf(hk2, C.wi[2], aiA); afA = fmaf(hk2, C.wf[2], afA);
    agA = fmaf(hk2, C.wg[2], agA); aoA = fmaf(hk2, C.wo[2], aoA);
    aiA = fmaf(hk3, C.wi[3], aiA); afA = fmaf(hk3, C.wf[3], afA);
    agA = fmaf(hk3, C.wg[3], agA); aoA = fmaf(hk3, C.wo[3], aoA);

    // half B: cross-quad slots (waits on DS results)
    float aiB = hk4 * C.wi[4];     float afB = hk4 * C.wf[4];
    float agB = hk4 * C.wg[4];     float aoB = hk4 * C.wo[4];
    aiB = fmaf(hk5, C.wi[5], aiB); afB = fmaf(hk5, C.wf[5], afB);
    agB = fmaf(hk5, C.wg[5], agB); aoB = fmaf(hk5, C.wo[5], aoB);
    aiB = fmaf(hk6, C.wi[6], aiB); afB = fmaf(hk6, C.wf[6], afB);
    agB = fmaf(hk6, C.wg[6], agB); aoB = fmaf(hk6, C.wo[6], aoB);
    aiB = fmaf(hk7, C.wi[7], aiB); afB = fmaf(hk7, C.wf[7], afB);
    agB = fmaf(hk7, C.wg[7], agB); aoB = fmaf(hk7, C.wo[7], aoB);

    // merge halves: g,i,f first (they gate the serial c-update), o last
    float zg = agA + agB;
    float zi = aiA + aiB;
    float zf = afA + afB;
    float zo = aoA + aoB;

    float eg = __builtin_amdgcn_exp2f(zg);   // e^{2g}
    float ei = __builtin_amdgcn_exp2f(zi);   // e^{-i}
    float ef = __builtin_amdgcn_exp2f(zf);   // e^{-f}
    float eo = __builtin_amdgcn_exp2f(zo);   // e^{-o}
    float di = 1.0f + ei, df = 1.0f + ef;
    float dg = 1.0f + eg, dz = 1.0f + eo;

    // paired reciprocals: 2 rcp for 4 gates
    float Ra = __builtin_amdgcn_rcpf(di * df);
    float sigi = Ra * df;                    // sigma(i)
    float sigf = Ra * di;                    // sigma(f)
    float Rb = __builtin_amdgcn_rcpf(dg * dz);
    float qg   = Rb * dz;                    // 1/(1+e^{2g})
    float sigo = Rb * dg;                    // sigma(o)

    // tgs = 2*log2(e) * tanh(g)
    float tgs = fmaf(-4.0f * LOG2E, qg, 2.0f * LOG2E);
    cs = fmaf(sigf, cs, sigi * tgs);         // scaled cell update
    // tanh(c) = 1 - 2/(1+e^{2c}), and e^{2c} = exp2(cs)
    float ec = __builtin_amdgcn_exp2f(cs);
    float qc = __builtin_amdgcn_rcpf(1.0f + ec);
    h = sigo * fmaf(-2.0f, qc, 1.0f);
}

__global__ __launch_bounds__(256, 2) void bilstm_kernel(
    const float* __restrict__ x, const float* __restrict__ h0, const float* __restrict__ c0,
    const float* __restrict__ w_ih_f, const float* __restrict__ w_hh_f, const float* __restrict__ b_f,
    const float* __restrict__ w_ih_b, const float* __restrict__ w_hh_b, const float* __restrict__ b_b,
    const float* __restrict__ w_lin, const float* __restrict__ b_lin,
    float* __restrict__ out, int B, int T)
{
    int tid = blockIdx.x * 256 + threadIdx.x;
    int b = tid >> 3;
    int j = tid & 7;
    int qp = (threadIdx.x >> 2) & 1;   // quad parity within the 8-lane group
    if (b >= B) return;

    Ctx Cf;
    load_ctx(Cf, j, qp, w_ih_f, w_hh_f, b_f);

    float h  = h0[(size_t)b * 8 + j];
    float cs = c0[(size_t)b * 8 + j] * (2.0f * LOG2E);

    const float4* xr = (const float4*)(x + (size_t)b * T);
    int nT4 = T >> 2;
    float4 xv = xr[0];
    // software pipeline: load group t4+1 unconditionally, use group t4
    for (int t4 = 0; t4 < nT4 - 1; ++t4) {
        float4 nxt = xr[t4 + 1];
        lstm_step(xv.x, h, cs, Cf);
        lstm_step(xv.y, h, cs, Cf);
        lstm_step(xv.z, h, cs, Cf);
        lstm_step(xv.w, h, cs, Cf);
        xv = nxt;
    }
    // epilogue: last group
    lstm_step(xv.x, h, cs, Cf);
    lstm_step(xv.y, h, cs, Cf);
    lstm_step(xv.z, h, cs, Cf);
    float xlast = xv.w;
    lstm_step(xlast, h, cs, Cf);

    // backward direction: exactly one step on x[:, T-1] (== xv.w)
    Ctx Cb;
    load_ctx(Cb, j, qp, w_ih_b, w_hh_b, b_b);
    float hb  = h0[(size_t)B * 8 + (size_t)b * 8 + j];
    float cbs = c0[(size_t)B * 8 + (size_t)b * 8 + j] * (2.0f * LOG2E);
    lstm_step(xlast, hb, cbs, Cb);

    // final linear: out[b] = sum_j h[j]*wl[j] + hb[j]*wl[8+j] + b_lin
    float part = fmaf(h, w_lin[j], hb * w_lin[8 + j]);
    part += __shfl_xor(part, 1, 8);
    part += __shfl_xor(part, 2, 8);
    part += __shfl_xor(part, 4, 8);
    if (j == 0) out[b] = part + b_lin[0];
}

extern "C" void kernel_launch(void* const* d_in, const int* in_sizes, int n_in,
                              void* d_out, int out_size, void* d_ws, size_t ws_size,
                              hipStream_t stream)
{
    const float* x      = (const float*)d_in[0];
    const float* h0     = (const float*)d_in[1];
    const float* c0     = (const float*)d_in[2];
    const float* w_ih_f = (const float*)d_in[3];
    const float* w_hh_f = (const float*)d_in[4];
    const float* b_f    = (const float*)d_in[5];
    const float* w_ih_b = (const float*)d_in[6];
    const float* w_hh_b = (const float*)d_in[7];
    const float* b_b    = (const float*)d_in[8];
    const float* w_lin  = (const float*)d_in[9];
    const float* b_lin  = (const float*)d_in[10];
    float* out = (float*)d_out;

    int B = in_sizes[1] / 16;   // h0: (2, B, 8)
    int T = in_sizes[0] / B;    // x:  (B, T, 1)

    int threads = B * 8;
    dim3 block(256);
    dim3 grid((threads + 255) / 256);
    hipLaunchKernelGGL(bilstm_kernel, grid, block, 0, stream,
                       x, h0, c0, w_ih_f, w_hh_f, b_f, w_ih_b, w_hh_b, b_b,
                       w_lin, b_lin, out, B, T);
}

// Round 14
// 125.000 us; speedup vs baseline: 1.1856x; 1.0103x over previous
//
#include <hip/hip_runtime.h>

// Bidirectional LSTM, B=16384 T=512 I=1 H=8, + final linear on [h_f(T-1), h_b(T-1)].
// Backward direction's state at time T-1 is its FIRST scan step -> one step only.
//
// R14 = R13 with the f16 vector type fixed (__fp16, matching the builtins'
// signatures on this clang).
//  - Recurrent dots via v_dot2_f32_f16 (full-rate, f32 accumulate): 32 FMA ->
//    16 fdot2 (+4 cvt_pkrtz to pack broadcast h into half2). Weights pre-scaled
//    and packed to half2 at setup (RTN casts). x path stays f32.
//  - ONE rcp serves all 4 gates: R = rcp(di*df*dg*do) (overflow-safe: |z|<~5
//    with 0.1-scale weights -> product <= ~1e8). Trans 8 -> 7 per step.
//  - Kept: 8 lanes/elem, hybrid broadcast (4 quad_perm DPP + 4 cross-quad
//    ds_swizzle), activation scales folded into weights (i,f,o x -log2e;
//    g x +2log2e), cell pre-scaled by 2log2e, unconditional 1-deep x prefetch.
//  Precision: h,w_hh in f16 (~5e-4 rel) -> expected absmax ~1e-3 vs threshold
//  5.078e-3 (fp32 rounds were 7.6e-6; trades slack for ~20% issue).

#define LOG2E 1.4426950408889634f

typedef __fp16 h2 __attribute__((ext_vector_type(2)));

// quad_perm broadcast lane k within each 4-lane quad (k = 0..3): ctrl = k * 0x55
#define DPPQ(v, k) __int_as_float(__builtin_amdgcn_update_dpp(0, __float_as_int(v), ((k) * 0x55), 0xF, 0xF, true))
// cross-quad pull: src = ((i & 0x1C) | k) ^ 4  -> quad0 gets h[4+k], quad1 gets h[k]
#define SWZX(v, k) __int_as_float(__builtin_amdgcn_ds_swizzle(__float_as_int(v), ((4 << 10) | ((k) << 5) | 0x1C)))

struct Ctx {
    h2 wi2[4], wf2[4], wg2[4], wo2[4];  // recurrent rows: pre-scaled, slot-permuted, f16-packed
    float xi, xf, xg, xo;               // input weights, pre-scaled (f32)
    float bi, bf, bg, bo;               // biases, pre-scaled (f32)
};

__device__ __forceinline__ void load_ctx(Ctx& C, int j, int qp,
    const float* __restrict__ w_ih, const float* __restrict__ w_hh,
    const float* __restrict__ b)
{
    // slot k -> h index: k<4 -> qp*4+k ; k>=4 -> (1-qp)*4 + (k-4)
    int own = qp * 4;
    int oth = 4 - own;
    const float si = -LOG2E;           // sigma rows: e = exp2(-z*log2e) = e^-z
    const float sg = 2.0f * LOG2E;     // tanh row:  e = exp2(2z*log2e) = e^{2z}

    const float* ri = w_hh + (size_t)j * 8;
    const float* rf = w_hh + (size_t)(8 + j) * 8;
    const float* rg = w_hh + (size_t)(16 + j) * 8;
    const float* ro = w_hh + (size_t)(24 + j) * 8;
#pragma unroll
    for (int p = 0; p < 4; ++p) {
        int k0 = 2 * p, k1 = 2 * p + 1;
        int s0 = (k0 < 4) ? (own + k0) : (oth + k0 - 4);
        int s1 = (k1 < 4) ? (own + k1) : (oth + k1 - 4);
        C.wi2[p] = h2{(__fp16)(ri[s0] * si), (__fp16)(ri[s1] * si)};
        C.wf2[p] = h2{(__fp16)(rf[s0] * si), (__fp16)(rf[s1] * si)};
        C.wg2[p] = h2{(__fp16)(rg[s0] * sg), (__fp16)(rg[s1] * sg)};
        C.wo2[p] = h2{(__fp16)(ro[s0] * si), (__fp16)(ro[s1] * si)};
    }
    C.xi = w_ih[j] * si;      C.bi = b[j] * si;
    C.xf = w_ih[8 + j] * si;  C.bf = b[8 + j] * si;
    C.xg = w_ih[16 + j] * sg; C.bg = b[16 + j] * sg;
    C.xo = w_ih[24 + j] * si; C.bo = b[24 + j] * si;
}

// cs is the cell state pre-scaled by 2*log2(e).
__device__ __forceinline__ void lstm_step(float xt, float& h, float& cs, const Ctx& C)
{
    // slots 4-7: cross-quad values via DS pipe (issued first; latency hidden
    // under the own-quad work)
    float hk4 = SWZX(h, 0);
    float hk5 = SWZX(h, 1);
    float hk6 = SWZX(h, 2);
    float hk7 = SWZX(h, 3);
    // slots 0-3: own-quad values via quad_perm DPP (ready immediately)
    float hk0 = DPPQ(h, 0);
    float hk1 = DPPQ(h, 1);
    float hk2 = DPPQ(h, 2);
    float hk3 = DPPQ(h, 3);

    // pack h pairs to half2 (v_cvt_pkrtz_f16_f32, 1 op per pair)
    h2 h01 = __builtin_amdgcn_cvt_pkrtz(hk0, hk1);
    h2 h23 = __builtin_amdgcn_cvt_pkrtz(hk2, hk3);
    h2 h45 = __builtin_amdgcn_cvt_pkrtz(hk4, hk5);
    h2 h67 = __builtin_amdgcn_cvt_pkrtz(hk6, hk7);

    // gate dots: f32 x-init + 4 chained v_dot2_f32_f16 each
    float zi = fmaf(xt, C.xi, C.bi);
    float zf = fmaf(xt, C.xf, C.bf);
    float zg = fmaf(xt, C.xg, C.bg);
    float zo = fmaf(xt, C.xo, C.bo);
    zi = __builtin_amdgcn_fdot2(h01, C.wi2[0], zi, false);
    zf = __builtin_amdgcn_fdot2(h01, C.wf2[0], zf, false);
    zg = __builtin_amdgcn_fdot2(h01, C.wg2[0], zg, false);
    zo = __builtin_amdgcn_fdot2(h01, C.wo2[0], zo, false);
    zi = __builtin_amdgcn_fdot2(h23, C.wi2[1], zi, false);
    zf = __builtin_amdgcn_fdot2(h23, C.wf2[1], zf, false);
    zg = __builtin_amdgcn_fdot2(h23, C.wg2[1], zg, false);
    zo = __builtin_amdgcn_fdot2(h23, C.wo2[1], zo, false);
    zi = __builtin_amdgcn_fdot2(h45, C.wi2[2], zi, false);
    zf = __builtin_amdgcn_fdot2(h45, C.wf2[2], zf, false);
    zg = __builtin_amdgcn_fdot2(h45, C.wg2[2], zg, false);
    zo = __builtin_amdgcn_fdot2(h45, C.wo2[2], zo, false);
    zi = __builtin_amdgcn_fdot2(h67, C.wi2[3], zi, false);
    zf = __builtin_amdgcn_fdot2(h67, C.wf2[3], zf, false);
    zg = __builtin_amdgcn_fdot2(h67, C.wg2[3], zg, false);
    zo = __builtin_amdgcn_fdot2(h67, C.wo2[3], zo, false);

    float eg = __builtin_amdgcn_exp2f(zg);   // e^{2g}
    float ei = __builtin_amdgcn_exp2f(zi);   // e^{-i}
    float ef = __builtin_amdgcn_exp2f(zf);   // e^{-f}
    float eo = __builtin_amdgcn_exp2f(zo);   // e^{-o}
    float di = 1.0f + ei, df = 1.0f + ef;
    float dg = 1.0f + eg, dz = 1.0f + eo;

    // ONE rcp for all 4 gates (overflow-safe: product <= ~1e8 here)
    float d12 = di * df;
    float d34 = dg * dz;
    float R = __builtin_amdgcn_rcpf(d12 * d34);
    float t34 = R * d34;                     // 1/(di*df)
    float t12 = R * d12;                     // 1/(dg*dz)
    float sigi = t34 * df;                   // sigma(i)
    float sigf = t34 * di;                   // sigma(f)
    float qg   = t12 * dz;                   // 1/(1+e^{2g})
    float sigo = t12 * dg;                   // sigma(o)

    // tgs = 2*log2(e) * tanh(g)
    float tgs = fmaf(-4.0f * LOG2E, qg, 2.0f * LOG2E);
    cs = fmaf(sigf, cs, sigi * tgs);         // scaled cell update
    // tanh(c) = 1 - 2/(1+e^{2c}), and e^{2c} = exp2(cs)
    float ec = __builtin_amdgcn_exp2f(cs);
    float qc = __builtin_amdgcn_rcpf(1.0f + ec);
    h = sigo * fmaf(-2.0f, qc, 1.0f);
}

__global__ __launch_bounds__(256, 2) void bilstm_kernel(
    const float* __restrict__ x, const float* __restrict__ h0, const float* __restrict__ c0,
    const float* __restrict__ w_ih_f, const float* __restrict__ w_hh_f, const float* __restrict__ b_f,
    const float* __restrict__ w_ih_b, const float* __restrict__ w_hh_b, const float* __restrict__ b_b,
    const float* __restrict__ w_lin, const float* __restrict__ b_lin,
    float* __restrict__ out, int B, int T)
{
    int tid = blockIdx.x * 256 + threadIdx.x;
    int b = tid >> 3;
    int j = tid & 7;
    int qp = (threadIdx.x >> 2) & 1;   // quad parity within the 8-lane group
    if (b >= B) return;

    Ctx Cf;
    load_ctx(Cf, j, qp, w_ih_f, w_hh_f, b_f);

    float h  = h0[(size_t)b * 8 + j];
    float cs = c0[(size_t)b * 8 + j] * (2.0f * LOG2E);

    const float4* xr = (const float4*)(x + (size_t)b * T);
    int nT4 = T >> 2;
    float4 xv = xr[0];
    // software pipeline: load group t4+1 unconditionally, use group t4
    for (int t4 = 0; t4 < nT4 - 1; ++t4) {
        float4 nxt = xr[t4 + 1];
        lstm_step(xv.x, h, cs, Cf);
        lstm_step(xv.y, h, cs, Cf);
        lstm_step(xv.z, h, cs, Cf);
        lstm_step(xv.w, h, cs, Cf);
        xv = nxt;
    }
    // epilogue: last group
    lstm_step(xv.x, h, cs, Cf);
    lstm_step(xv.y, h, cs, Cf);
    lstm_step(xv.z, h, cs, Cf);
    float xlast = xv.w;
    lstm_step(xlast, h, cs, Cf);

    // backward direction: exactly one step on x[:, T-1] (== xv.w)
    Ctx Cb;
    load_ctx(Cb, j, qp, w_ih_b, w_hh_b, b_b);
    float hb  = h0[(size_t)B * 8 + (size_t)b * 8 + j];
    float cbs = c0[(size_t)B * 8 + (size_t)b * 8 + j] * (2.0f * LOG2E);
    lstm_step(xlast, hb, cbs, Cb);

    // final linear: out[b] = sum_j h[j]*wl[j] + hb[j]*wl[8+j] + b_lin
    float part = fmaf(h, w_lin[j], hb * w_lin[8 + j]);
    part += __shfl_xor(part, 1, 8);
    part += __shfl_xor(part, 2, 8);
    part += __shfl_xor(part, 4, 8);
    if (j == 0) out[b] = part + b_lin[0];
}

extern "C" void kernel_launch(void* const* d_in, const int* in_sizes, int n_in,
                              void* d_out, int out_size, void* d_ws, size_t ws_size,
                              hipStream_t stream)
{
    const float* x      = (const float*)d_in[0];
    const float* h0     = (const float*)d_in[1];
    const float* c0     = (const float*)d_in[2];
    const float* w_ih_f = (const float*)d_in[3];
    const float* w_hh_f = (const float*)d_in[4];
    const float* b_f    = (const float*)d_in[5];
    const float* w_ih_b = (const float*)d_in[6];
    const float* w_hh_b = (const float*)d_in[7];
    const float* b_b    = (const float*)d_in[8];
    const float* w_lin  = (const float*)d_in[9];
    const float* b_lin  = (const float*)d_in[10];
    float* out = (float*)d_out;

    int B = in_sizes[1] / 16;   // h0: (2, B, 8)
    int T = in_sizes[0] / B;    // x:  (B, T, 1)

    int threads = B * 8;
    dim3 block(256);
    dim3 grid((threads + 255) / 256);
    hipLaunchKernelGGL(bilstm_kernel, grid, block, 0, stream,
                       x, h0, c0, w_ih_f, w_hh_f, b_f, w_ih_b, w_hh_b, b_b,
                       w_lin, b_lin, out, B, T);
}

// Round 15
// 117.048 us; speedup vs baseline: 1.2661x; 1.0679x over previous
//
#include <hip/hip_runtime.h>

// Bidirectional LSTM, B=16384 T=512 I=1 H=8, + final linear on [h_f(T-1), h_b(T-1)].
// Backward direction's state at time T-1 is its FIRST scan step -> one step only.
//
// R15 = R14 (fdot2 gates, 1-rcp-for-4-gates, folded scales, prescaled cell,
// pipelined x prefetch) + ZERO-DS packed broadcast:
//   hm = row_half_mirror(h)         1 DPP   (lane i&7 -> h[7-(i&7)])
//   ph = cvt_pkrtz(h, hm)           1 VALU  (packed {h_l, h_mirror(l)})
//   pk = quad_perm(ph, k), k=0..3   4 DPP   (32-bit move of the packed pair)
// Lane in quad q receives pairs {h[4q+k], h[7-4q-k]} -- all 8 h values exactly
// once. fdot2 weight pairs are pre-packed to match: w2[p] = {w[4qp+p],
// w[7-4qp-p]}. Replaces 4 ds_swizzle + 4 DPP + 4 cvt: the ~140-cyc DS latency
// leaves the h(t)->h(t+1) critical chain (was ~270 cyc; 2 waves/SIMD could not
// hide it -- R8..R14 all showed issue cuts converting to stall).
// NOTE: R6's full-DPP test was confounded by a 2 MB prefetch scratch spill;
// this is the clean test of the all-VALU broadcast.

#define LOG2E 1.4426950408889634f

typedef __fp16 h2 __attribute__((ext_vector_type(2)));

// DPP move of a float: ctrl 0x141 = row_half_mirror (8-lane-group preserving)
#define DPPF(v, ctrl) __int_as_float(__builtin_amdgcn_update_dpp(0, __float_as_int(v), (ctrl), 0xF, 0xF, true))
// DPP move of a packed h2 (32-bit): quad_perm broadcast k = k*0x55
#define DPPQH(v, k) __builtin_bit_cast(h2, __builtin_amdgcn_update_dpp(0, __builtin_bit_cast(int, (v)), ((k) * 0x55), 0xF, 0xF, true))

struct Ctx {
    h2 wi2[4], wf2[4], wg2[4], wo2[4];  // pre-scaled, pair-packed to DPP delivery
    float xi, xf, xg, xo;               // input weights, pre-scaled (f32)
    float bi, bf, bg, bo;               // biases, pre-scaled (f32)
};

__device__ __forceinline__ void load_ctx(Ctx& C, int j, int qp,
    const float* __restrict__ w_ih, const float* __restrict__ w_hh,
    const float* __restrict__ b)
{
    const float si = -LOG2E;           // sigma rows: e = exp2(-z*log2e) = e^-z
    const float sg = 2.0f * LOG2E;     // tanh row:  e = exp2(2z*log2e) = e^{2z}

    const float* ri = w_hh + (size_t)j * 8;
    const float* rf = w_hh + (size_t)(8 + j) * 8;
    const float* rg = w_hh + (size_t)(16 + j) * 8;
    const float* ro = w_hh + (size_t)(24 + j) * 8;
#pragma unroll
    for (int p = 0; p < 4; ++p) {
        int s0 = 4 * qp + p;           // pair element 0: own-quad value
        int s1 = 7 - 4 * qp - p;       // pair element 1: mirrored value
        C.wi2[p] = h2{(__fp16)(ri[s0] * si), (__fp16)(ri[s1] * si)};
        C.wf2[p] = h2{(__fp16)(rf[s0] * si), (__fp16)(rf[s1] * si)};
        C.wg2[p] = h2{(__fp16)(rg[s0] * sg), (__fp16)(rg[s1] * sg)};
        C.wo2[p] = h2{(__fp16)(ro[s0] * si), (__fp16)(ro[s1] * si)};
    }
    C.xi = w_ih[j] * si;      C.bi = b[j] * si;
    C.xf = w_ih[8 + j] * si;  C.bf = b[8 + j] * si;
    C.xg = w_ih[16 + j] * sg; C.bg = b[16 + j] * sg;
    C.xo = w_ih[24 + j] * si; C.bo = b[24 + j] * si;
}

// cs is the cell state pre-scaled by 2*log2(e).
__device__ __forceinline__ void lstm_step(float xt, float& h, float& cs, const Ctx& C)
{
    // all-VALU packed broadcast: 1 mirror + 1 pack + 4 quad_perm
    float hm = DPPF(h, 0x141);                    // h[7-(i&7)] within 8-group
    h2 ph = __builtin_amdgcn_cvt_pkrtz(h, hm);    // {h_l, h_mirror(l)} packed
    h2 p0 = DPPQH(ph, 0);
    h2 p1 = DPPQH(ph, 1);
    h2 p2 = DPPQH(ph, 2);
    h2 p3 = DPPQH(ph, 3);

    // gate dots: f32 x-init + 4 chained v_dot2_f32_f16 each
    float zi = fmaf(xt, C.xi, C.bi);
    float zf = fmaf(xt, C.xf, C.bf);
    float zg = fmaf(xt, C.xg, C.bg);
    float zo = fmaf(xt, C.xo, C.bo);
    zi = __builtin_amdgcn_fdot2(p0, C.wi2[0], zi, false);
    zf = __builtin_amdgcn_fdot2(p0, C.wf2[0], zf, false);
    zg = __builtin_amdgcn_fdot2(p0, C.wg2[0], zg, false);
    zo = __builtin_amdgcn_fdot2(p0, C.wo2[0], zo, false);
    zi = __builtin_amdgcn_fdot2(p1, C.wi2[1], zi, false);
    zf = __builtin_amdgcn_fdot2(p1, C.wf2[1], zf, false);
    zg = __builtin_amdgcn_fdot2(p1, C.wg2[1], zg, false);
    zo = __builtin_amdgcn_fdot2(p1, C.wo2[1], zo, false);
    zi = __builtin_amdgcn_fdot2(p2, C.wi2[2], zi, false);
    zf = __builtin_amdgcn_fdot2(p2, C.wf2[2], zf, false);
    zg = __builtin_amdgcn_fdot2(p2, C.wg2[2], zg, false);
    zo = __builtin_amdgcn_fdot2(p2, C.wo2[2], zo, false);
    zi = __builtin_amdgcn_fdot2(p3, C.wi2[3], zi, false);
    zf = __builtin_amdgcn_fdot2(p3, C.wf2[3], zf, false);
    zg = __builtin_amdgcn_fdot2(p3, C.wg2[3], zg, false);
    zo = __builtin_amdgcn_fdot2(p3, C.wo2[3], zo, false);

    float eg = __builtin_amdgcn_exp2f(zg);   // e^{2g}
    float ei = __builtin_amdgcn_exp2f(zi);   // e^{-i}
    float ef = __builtin_amdgcn_exp2f(zf);   // e^{-f}
    float eo = __builtin_amdgcn_exp2f(zo);   // e^{-o}
    float di = 1.0f + ei, df = 1.0f + ef;
    float dg = 1.0f + eg, dz = 1.0f + eo;

    // ONE rcp for all 4 gates (overflow-safe: product <= ~1e8 here)
    float d12 = di * df;
    float d34 = dg * dz;
    float R = __builtin_amdgcn_rcpf(d12 * d34);
    float t34 = R * d34;                     // 1/(di*df)
    float t12 = R * d12;                     // 1/(dg*dz)
    float sigi = t34 * df;                   // sigma(i)
    float sigf = t34 * di;                   // sigma(f)
    float qg   = t12 * dz;                   // 1/(1+e^{2g})
    float sigo = t12 * dg;                   // sigma(o)

    // tgs = 2*log2(e) * tanh(g)
    float tgs = fmaf(-4.0f * LOG2E, qg, 2.0f * LOG2E);
    cs = fmaf(sigf, cs, sigi * tgs);         // scaled cell update
    // tanh(c) = 1 - 2/(1+e^{2c}), and e^{2c} = exp2(cs)
    float ec = __builtin_amdgcn_exp2f(cs);
    float qc = __builtin_amdgcn_rcpf(1.0f + ec);
    h = sigo * fmaf(-2.0f, qc, 1.0f);
}

__global__ __launch_bounds__(256, 2) void bilstm_kernel(
    const float* __restrict__ x, const float* __restrict__ h0, const float* __restrict__ c0,
    const float* __restrict__ w_ih_f, const float* __restrict__ w_hh_f, const float* __restrict__ b_f,
    const float* __restrict__ w_ih_b, const float* __restrict__ w_hh_b, const float* __restrict__ b_b,
    const float* __restrict__ w_lin, const float* __restrict__ b_lin,
    float* __restrict__ out, int B, int T)
{
    int tid = blockIdx.x * 256 + threadIdx.x;
    int b = tid >> 3;
    int j = tid & 7;
    int qp = (threadIdx.x >> 2) & 1;   // quad parity within the 8-lane group
    if (b >= B) return;

    Ctx Cf;
    load_ctx(Cf, j, qp, w_ih_f, w_hh_f, b_f);

    float h  = h0[(size_t)b * 8 + j];
    float cs = c0[(size_t)b * 8 + j] * (2.0f * LOG2E);

    const float4* xr = (const float4*)(x + (size_t)b * T);
    int nT4 = T >> 2;
    float4 xv = xr[0];
    // software pipeline: load group t4+1 unconditionally, use group t4
    for (int t4 = 0; t4 < nT4 - 1; ++t4) {
        float4 nxt = xr[t4 + 1];
        lstm_step(xv.x, h, cs, Cf);
        lstm_step(xv.y, h, cs, Cf);
        lstm_step(xv.z, h, cs, Cf);
        lstm_step(xv.w, h, cs, Cf);
        xv = nxt;
    }
    // epilogue: last group
    lstm_step(xv.x, h, cs, Cf);
    lstm_step(xv.y, h, cs, Cf);
    lstm_step(xv.z, h, cs, Cf);
    float xlast = xv.w;
    lstm_step(xlast, h, cs, Cf);

    // backward direction: exactly one step on x[:, T-1] (== xv.w)
    Ctx Cb;
    load_ctx(Cb, j, qp, w_ih_b, w_hh_b, b_b);
    float hb  = h0[(size_t)B * 8 + (size_t)b * 8 + j];
    float cbs = c0[(size_t)B * 8 + (size_t)b * 8 + j] * (2.0f * LOG2E);
    lstm_step(xlast, hb, cbs, Cb);

    // final linear: out[b] = sum_j h[j]*wl[j] + hb[j]*wl[8+j] + b_lin
    float part = fmaf(h, w_lin[j], hb * w_lin[8 + j]);
    part += __shfl_xor(part, 1, 8);
    part += __shfl_xor(part, 2, 8);
    part += __shfl_xor(part, 4, 8);
    if (j == 0) out[b] = part + b_lin[0];
}

extern "C" void kernel_launch(void* const* d_in, const int* in_sizes, int n_in,
                              void* d_out, int out_size, void* d_ws, size_t ws_size,
                              hipStream_t stream)
{
    const float* x      = (const float*)d_in[0];
    const float* h0     = (const float*)d_in[1];
    const float* c0     = (const float*)d_in[2];
    const float* w_ih_f = (const float*)d_in[3];
    const float* w_hh_f = (const float*)d_in[4];
    const float* b_f    = (const float*)d_in[5];
    const float* w_ih_b = (const float*)d_in[6];
    const float* w_hh_b = (const float*)d_in[7];
    const float* b_b    = (const float*)d_in[8];
    const float* w_lin  = (const float*)d_in[9];
    const float* b_lin  = (const float*)d_in[10];
    float* out = (float*)d_out;

    int B = in_sizes[1] / 16;   // h0: (2, B, 8)
    int T = in_sizes[0] / B;    // x:  (B, T, 1)

    int threads = B * 8;
    dim3 block(256);
    dim3 grid((threads + 255) / 256);
    hipLaunchKernelGGL(bilstm_kernel, grid, block, 0, stream,
                       x, h0, c0, w_ih_f, w_hh_f, b_f, w_ih_b, w_hh_b, b_b,
                       w_lin, b_lin, out, B, T);
}

// Round 16
// 105.194 us; speedup vs baseline: 1.4088x; 1.1127x over previous
//
#include <hip/hip_runtime.h>

// Bidirectional LSTM, B=16384 T=512 I=1 H=8, + final linear on [h_f(T-1), h_b(T-1)].
// Backward direction's state at time T-1 is its FIRST scan step -> one step only.
//
// R16 = R15 x ILP-2: two independent batch elements per thread.
//  R15 (kept): zero-DS packed broadcast (1 row_half_mirror DPP + 1 cvt_pkrtz +
//  4 quad_perm DPP on the packed pair), fdot2 gate dots with pair-packed f16
//  weights, ONE rcp for 4 gates, folded activation scales, cell pre-scaled by
//  2log2e, unconditional pipelined x prefetch.
//  New: each thread advances elements e0=2p, e1=2p+1 together (weights shared).
//  Grid: (B/2)*8 = 1024 waves = 1 wave/SIMD. Element B's instruction stream
//  fills element A's ~150-cyc serial tail (and vice versa). R10's ILP-2 failed
//  because DS swizzle lgkmcnt waits are WAVE-WIDE and serialized both streams;
//  R15's loop has zero DS ops, so the two streams interleave freely.

#define LOG2E 1.4426950408889634f

typedef __fp16 h2 __attribute__((ext_vector_type(2)));

// DPP move of a float: ctrl 0x141 = row_half_mirror (8-lane-group preserving)
#define DPPF(v, ctrl) __int_as_float(__builtin_amdgcn_update_dpp(0, __float_as_int(v), (ctrl), 0xF, 0xF, true))
// DPP move of a packed h2 (32-bit): quad_perm broadcast k = k*0x55
#define DPPQH(v, k) __builtin_bit_cast(h2, __builtin_amdgcn_update_dpp(0, __builtin_bit_cast(int, (v)), ((k) * 0x55), 0xF, 0xF, true))

struct Ctx {
    h2 wi2[4], wf2[4], wg2[4], wo2[4];  // pre-scaled, pair-packed to DPP delivery
    float xi, xf, xg, xo;               // input weights, pre-scaled (f32)
    float bi, bf, bg, bo;               // biases, pre-scaled (f32)
};

__device__ __forceinline__ void load_ctx(Ctx& C, int j, int qp,
    const float* __restrict__ w_ih, const float* __restrict__ w_hh,
    const float* __restrict__ b)
{
    const float si = -LOG2E;           // sigma rows: e = exp2(-z*log2e) = e^-z
    const float sg = 2.0f * LOG2E;     // tanh row:  e = exp2(2z*log2e) = e^{2z}

    const float* ri = w_hh + (size_t)j * 8;
    const float* rf = w_hh + (size_t)(8 + j) * 8;
    const float* rg = w_hh + (size_t)(16 + j) * 8;
    const float* ro = w_hh + (size_t)(24 + j) * 8;
#pragma unroll
    for (int p = 0; p < 4; ++p) {
        int s0 = 4 * qp + p;           // pair element 0: own-quad value
        int s1 = 7 - 4 * qp - p;       // pair element 1: mirrored value
        C.wi2[p] = h2{(__fp16)(ri[s0] * si), (__fp16)(ri[s1] * si)};
        C.wf2[p] = h2{(__fp16)(rf[s0] * si), (__fp16)(rf[s1] * si)};
        C.wg2[p] = h2{(__fp16)(rg[s0] * sg), (__fp16)(rg[s1] * sg)};
        C.wo2[p] = h2{(__fp16)(ro[s0] * si), (__fp16)(ro[s1] * si)};
    }
    C.xi = w_ih[j] * si;      C.bi = b[j] * si;
    C.xf = w_ih[8 + j] * si;  C.bf = b[8 + j] * si;
    C.xg = w_ih[16 + j] * sg; C.bg = b[16 + j] * sg;
    C.xo = w_ih[24 + j] * si; C.bo = b[24 + j] * si;
}

// One LSTM step for one element (all-VALU; no DS).
__device__ __forceinline__ void lstm_step1(float xt, float& h, float& cs, const Ctx& C)
{
    float hm = DPPF(h, 0x141);                    // h[7-(i&7)] within 8-group
    h2 ph = __builtin_amdgcn_cvt_pkrtz(h, hm);    // {h_l, h_mirror(l)} packed
    h2 p0 = DPPQH(ph, 0);
    h2 p1 = DPPQH(ph, 1);
    h2 p2 = DPPQH(ph, 2);
    h2 p3 = DPPQH(ph, 3);

    float zi = fmaf(xt, C.xi, C.bi);
    float zf = fmaf(xt, C.xf, C.bf);
    float zg = fmaf(xt, C.xg, C.bg);
    float zo = fmaf(xt, C.xo, C.bo);
    zi = __builtin_amdgcn_fdot2(p0, C.wi2[0], zi, false);
    zf = __builtin_amdgcn_fdot2(p0, C.wf2[0], zf, false);
    zg = __builtin_amdgcn_fdot2(p0, C.wg2[0], zg, false);
    zo = __builtin_amdgcn_fdot2(p0, C.wo2[0], zo, false);
    zi = __builtin_amdgcn_fdot2(p1, C.wi2[1], zi, false);
    zf = __builtin_amdgcn_fdot2(p1, C.wf2[1], zf, false);
    zg = __builtin_amdgcn_fdot2(p1, C.wg2[1], zg, false);
    zo = __builtin_amdgcn_fdot2(p1, C.wo2[1], zo, false);
    zi = __builtin_amdgcn_fdot2(p2, C.wi2[2], zi, false);
    zf = __builtin_amdgcn_fdot2(p2, C.wf2[2], zf, false);
    zg = __builtin_amdgcn_fdot2(p2, C.wg2[2], zg, false);
    zo = __builtin_amdgcn_fdot2(p2, C.wo2[2], zo, false);
    zi = __builtin_amdgcn_fdot2(p3, C.wi2[3], zi, false);
    zf = __builtin_amdgcn_fdot2(p3, C.wf2[3], zf, false);
    zg = __builtin_amdgcn_fdot2(p3, C.wg2[3], zg, false);
    zo = __builtin_amdgcn_fdot2(p3, C.wo2[3], zo, false);

    float eg = __builtin_amdgcn_exp2f(zg);   // e^{2g}
    float ei = __builtin_amdgcn_exp2f(zi);   // e^{-i}
    float ef = __builtin_amdgcn_exp2f(zf);   // e^{-f}
    float eo = __builtin_amdgcn_exp2f(zo);   // e^{-o}
    float di = 1.0f + ei, df = 1.0f + ef;
    float dg = 1.0f + eg, dz = 1.0f + eo;

    float d12 = di * df;
    float d34 = dg * dz;
    float R = __builtin_amdgcn_rcpf(d12 * d34);
    float t34 = R * d34;                     // 1/(di*df)
    float t12 = R * d12;                     // 1/(dg*dz)
    float sigi = t34 * df;                   // sigma(i)
    float sigf = t34 * di;                   // sigma(f)
    float qg   = t12 * dz;                   // 1/(1+e^{2g})
    float sigo = t12 * dg;                   // sigma(o)

    float tgs = fmaf(-4.0f * LOG2E, qg, 2.0f * LOG2E);   // 2log2e * tanh(g)
    cs = fmaf(sigf, cs, sigi * tgs);
    float ec = __builtin_amdgcn_exp2f(cs);
    float qc = __builtin_amdgcn_rcpf(1.0f + ec);
    h = sigo * fmaf(-2.0f, qc, 1.0f);
}

__global__ __launch_bounds__(256, 1) void bilstm_kernel(
    const float* __restrict__ x, const float* __restrict__ h0, const float* __restrict__ c0,
    const float* __restrict__ w_ih_f, const float* __restrict__ w_hh_f, const float* __restrict__ b_f,
    const float* __restrict__ w_ih_b, const float* __restrict__ w_hh_b, const float* __restrict__ b_b,
    const float* __restrict__ w_lin, const float* __restrict__ b_lin,
    float* __restrict__ out, int B, int T)
{
    int tid = blockIdx.x * 256 + threadIdx.x;
    int p = tid >> 3;                  // element-pair index
    int j = tid & 7;
    int qp = (threadIdx.x >> 2) & 1;   // quad parity within the 8-lane group
    if (p >= (B >> 1)) return;
    int e0 = 2 * p, e1 = 2 * p + 1;

    Ctx Cf;
    load_ctx(Cf, j, qp, w_ih_f, w_hh_f, b_f);

    float hA  = h0[(size_t)e0 * 8 + j];
    float hB  = h0[(size_t)e1 * 8 + j];
    float csA = c0[(size_t)e0 * 8 + j] * (2.0f * LOG2E);
    float csB = c0[(size_t)e1 * 8 + j] * (2.0f * LOG2E);

    const float4* xrA = (const float4*)(x + (size_t)e0 * T);
    const float4* xrB = (const float4*)(x + (size_t)e1 * T);
    int nT4 = T >> 2;
    float4 xvA = xrA[0];
    float4 xvB = xrB[0];
    // software pipeline: load group t4+1 unconditionally, use group t4
    for (int t4 = 0; t4 < nT4 - 1; ++t4) {
        float4 nA = xrA[t4 + 1];
        float4 nB = xrB[t4 + 1];
        lstm_step1(xvA.x, hA, csA, Cf); lstm_step1(xvB.x, hB, csB, Cf);
        lstm_step1(xvA.y, hA, csA, Cf); lstm_step1(xvB.y, hB, csB, Cf);
        lstm_step1(xvA.z, hA, csA, Cf); lstm_step1(xvB.z, hB, csB, Cf);
        lstm_step1(xvA.w, hA, csA, Cf); lstm_step1(xvB.w, hB, csB, Cf);
        xvA = nA; xvB = nB;
    }
    // epilogue: last group
    lstm_step1(xvA.x, hA, csA, Cf); lstm_step1(xvB.x, hB, csB, Cf);
    lstm_step1(xvA.y, hA, csA, Cf); lstm_step1(xvB.y, hB, csB, Cf);
    lstm_step1(xvA.z, hA, csA, Cf); lstm_step1(xvB.z, hB, csB, Cf);
    float xlastA = xvA.w, xlastB = xvB.w;
    lstm_step1(xlastA, hA, csA, Cf); lstm_step1(xlastB, hB, csB, Cf);

    // backward direction: exactly one step on x[:, T-1]
    Ctx Cb;
    load_ctx(Cb, j, qp, w_ih_b, w_hh_b, b_b);
    float hbA  = h0[(size_t)B * 8 + (size_t)e0 * 8 + j];
    float hbB  = h0[(size_t)B * 8 + (size_t)e1 * 8 + j];
    float cbA  = c0[(size_t)B * 8 + (size_t)e0 * 8 + j] * (2.0f * LOG2E);
    float cbB  = c0[(size_t)B * 8 + (size_t)e1 * 8 + j] * (2.0f * LOG2E);
    lstm_step1(xlastA, hbA, cbA, Cb);
    lstm_step1(xlastB, hbB, cbB, Cb);

    // final linear per element, reduced across the 8-lane group
    float pA = fmaf(hA, w_lin[j], hbA * w_lin[8 + j]);
    float pB = fmaf(hB, w_lin[j], hbB * w_lin[8 + j]);
    pA += __shfl_xor(pA, 1, 8);
    pB += __shfl_xor(pB, 1, 8);
    pA += __shfl_xor(pA, 2, 8);
    pB += __shfl_xor(pB, 2, 8);
    pA += __shfl_xor(pA, 4, 8);
    pB += __shfl_xor(pB, 4, 8);
    if (j == 0) {
        float bl = b_lin[0];
        out[e0] = pA + bl;
        out[e1] = pB + bl;
    }
}

extern "C" void kernel_launch(void* const* d_in, const int* in_sizes, int n_in,
                              void* d_out, int out_size, void* d_ws, size_t ws_size,
                              hipStream_t stream)
{
    const float* x      = (const float*)d_in[0];
    const float* h0     = (const float*)d_in[1];
    const float* c0     = (const float*)d_in[2];
    const float* w_ih_f = (const float*)d_in[3];
    const float* w_hh_f = (const float*)d_in[4];
    const float* b_f    = (const float*)d_in[5];
    const float* w_ih_b = (const float*)d_in[6];
    const float* w_hh_b = (const float*)d_in[7];
    const float* b_b    = (const float*)d_in[8];
    const float* w_lin  = (const float*)d_in[9];
    const float* b_lin  = (const float*)d_in[10];
    float* out = (float*)d_out;

    int B = in_sizes[1] / 16;   // h0: (2, B, 8)
    int T = in_sizes[0] / B;    // x:  (B, T, 1)

    int threads = (B / 2) * 8;
    dim3 block(256);
    dim3 grid((threads + 255) / 256);
    hipLaunchKernelGGL(bilstm_kernel, grid, block, 0, stream,
                       x, h0, c0, w_ih_f, w_hh_f, b_f, w_ih_b, w_hh_b, b_b,
                       w_lin, b_lin, out, B, T);
}